// Round 5
// baseline (392.136 us; speedup 1.0000x reference)
//
#include <hip/hip_runtime.h>
#include <hip/hip_bf16.h>

#define DEVI static __device__ __forceinline__

typedef __attribute__((ext_vector_type(8))) short short8;
typedef __attribute__((ext_vector_type(16))) float f32x16;
typedef __attribute__((ext_vector_type(2))) unsigned int uintx2;

#define S_LEN 2048
#define D_DIM 128
#define NBATCH 16
// (1/sqrt(128)) * log2(e): base-2 softmax, scale folded into Q conversion
#define QSC ((float)(0.08838834764831845 * 1.4426950408889634))

#if __has_builtin(__builtin_amdgcn_exp2f)
#define EXP2(x) __builtin_amdgcn_exp2f(x)
#else
#define EXP2(x) exp2f(x)
#endif

DEVI unsigned short f2bf(float x) {
  union { float f; unsigned int u; } a; a.f = x;
  unsigned int u = a.u;
  unsigned int r = (u + 0x7fffu + ((u >> 16) & 1u)) >> 16;
  return (unsigned short)r;
}

DEVI unsigned int cvtpk(float lo, float hi) {
  unsigned int r;
  asm volatile("v_cvt_pk_bf16_f32 %0, %1, %2" : "=v"(r) : "v"(lo), "v"(hi));
  return r;
}

// v_permlane32_swap_b32: swaps UPPER half of first arg with LOWER half of second.
// post: a = {a.lo | b.lo}, b = {a.hi | b.hi}   (verified R4)
DEVI void plswap(unsigned int& a, unsigned int& b) {
  uintx2 r = __builtin_amdgcn_permlane32_swap(a, b, false, false);
  a = r[0];
  b = r[1];
}

DEVI float xhalf_max(float x) {
  union { float f; unsigned int u; } a, b;
  a.f = x; b.f = x;
  plswap(a.u, b.u);
  return fmaxf(a.f, b.f);
}

DEVI float xhalf_sum(float x) {
  union { float f; unsigned int u; } a, b;
  a.f = x; b.f = x;
  plswap(a.u, b.u);
  return a.f + b.f;
}

// ---------------- prepass ----------------

// blocks [0,1024): V [b][s][d] fp32 -> Vt [b][d][s] bf16 + per-64-row tile sums
// blocks [1024,3072): K fp32 -> bf16
__global__ void prep(const float* __restrict__ K, const float* __restrict__ V,
                     unsigned short* __restrict__ Kb, unsigned short* __restrict__ Vt,
                     float* __restrict__ Tsum) {
  __shared__ unsigned short t[64][68];
  const int tt = threadIdx.x;
  if (blockIdx.x >= 1024) {
    const int M4 = (NBATCH * S_LEN * D_DIM) / 4;
    for (int i = (blockIdx.x - 1024) * 256 + tt; i < M4; i += 2048 * 256) {
      const size_t idx = (size_t)i * 4;
      const float4 v = *reinterpret_cast<const float4*>(K + idx);
      ushort4 o;
      o.x = f2bf(v.x); o.y = f2bf(v.y); o.z = f2bf(v.z); o.w = f2bf(v.w);
      *reinterpret_cast<ushort4*>(Kb + idx) = o;
    }
    return;
  }
  const int bid = blockIdx.x;
  const int b = bid >> 6, rem = bid & 63;
  const int st = rem & 31, s0 = st * 64, d0 = (rem >> 5) * 64;
  const int r = tt >> 2, c = (tt & 3) * 16;
  const float* src = V + ((size_t)(b * S_LEN + s0 + r)) * D_DIM + d0 + c;
#pragma unroll
  for (int i = 0; i < 4; i++) {
    float4 v = reinterpret_cast<const float4*>(src)[i];
    t[r][c + 4 * i + 0] = f2bf(v.x);
    t[r][c + 4 * i + 1] = f2bf(v.y);
    t[r][c + 4 * i + 2] = f2bf(v.z);
    t[r][c + 4 * i + 3] = f2bf(v.w);
  }
  __syncthreads();
  unsigned short* dst = Vt + ((size_t)(b * D_DIM + d0 + r)) * S_LEN + s0 + c;
#pragma unroll
  for (int i = 0; i < 4; i++) {
    ushort4 o;
    o.x = t[c + 4 * i + 0][r];
    o.y = t[c + 4 * i + 1][r];
    o.z = t[c + 4 * i + 2][r];
    o.w = t[c + 4 * i + 3][r];
    reinterpret_cast<ushort4*>(dst)[i] = o;
  }
  if (tt < 64) {
    float s = 0.0f;
#pragma unroll 8
    for (int rr = 0; rr < 64; rr++) {
      union { float f; unsigned int u; } cv;
      cv.u = ((unsigned int)t[rr][tt]) << 16;
      s += cv.f;
    }
    Tsum[((size_t)b * 32 + st) * 128 + d0 + tt] = s;
  }
}

// SufV[b][t][d] = sum_{t' >= t} Tsum[b][t'][d]; SufV[b][32][d] = 0
__global__ void sufB(const float* __restrict__ Tsum, float* __restrict__ SufV) {
  const int b = blockIdx.x;
  const int d = threadIdx.x;
  float v[32];
#pragma unroll
  for (int t = 0; t < 32; t++) v[t] = Tsum[((size_t)b * 32 + t) * 128 + d];
  float run = 0.0f;
  SufV[((size_t)b * 33 + 32) * 128 + d] = 0.0f;
#pragma unroll
  for (int t = 31; t >= 0; t--) {
    run += v[t];
    SufV[((size_t)b * 33 + t) * 128 + d] = run;
  }
}

// ---------------- attention kernel ----------------

DEVI void stage_tiles(char* ldsbuf, const unsigned short* Kb,
                      const unsigned short* Vt, int b, int kt, int w, int lane) {
  const int kv0 = kt * 64;
  if (w < 2) {
    // K tile: 64 rows x 256B contiguous; XOR-swizzle (16 slots) via pre-swizzled source
    const char* ktile = (const char*)(Kb + ((size_t)b * S_LEN + kv0) * D_DIM);
#pragma unroll
    for (int i = 0; i < 8; i++) {
      int c = w * 8 + i;
      int L = c * 1024 + lane * 16;
      int row = L >> 8;
      int src = row * 256 + ((L & 255) ^ ((row & 15) << 4));
      __builtin_amdgcn_global_load_lds(
          (const __attribute__((address_space(1))) unsigned int*)(ktile + src),
          (__attribute__((address_space(3))) unsigned int*)(ldsbuf + c * 1024),
          16, 0, 0);
    }
  } else {
    // V^T tile: 128 rows x 128B, row stride S*2 in global
    char* ldsV = ldsbuf + 16384;
#pragma unroll
    for (int i = 0; i < 8; i++) {
      int c = (w - 2) * 8 + i;
      int L = c * 1024 + lane * 16;
      int row = L >> 7;
      int xs = (L & 127) ^ ((row & 7) << 4);
      const char* src = (const char*)Vt +
                        (((size_t)b * D_DIM + row) * S_LEN + kv0) * 2 + xs;
      __builtin_amdgcn_global_load_lds(
          (const __attribute__((address_space(1))) unsigned int*)src,
          (__attribute__((address_space(3))) unsigned int*)(ldsV + c * 1024),
          16, 0, 0);
    }
  }
}

DEVI short8 ldK(const char* ldsK, int row, int off) {
  int addr = row * 256 + (off ^ ((row & 15) << 4));
  return *reinterpret_cast<const short8*>(ldsK + addr);
}
DEVI short8 ldV(const char* ldsV, int row, int off) {
  int addr = row * 128 + (off ^ ((row & 7) << 4));
  return *reinterpret_cast<const short8*>(ldsV + addr);
}

template <bool MASK>
DEVI void tile_body(const char* cb, const short8* qf, f32x16 (&acc)[4],
                    float& m_run, float& l_run, const int ln31, const int h,
                    const int kh, const int qrow, const int kvb) {
  // S^T = K_half * Q^T  (swapped operands: lane owns one q column)
  f32x16 sT;
#pragma unroll
  for (int r = 0; r < 16; r++) sT[r] = 0.0f;
#pragma unroll
  for (int kf = 0; kf < 8; kf++) {
    short8 af = ldK(cb, ln31 + 32 * kh, 32 * kf + 16 * h);
    sT = __builtin_amdgcn_mfma_f32_32x32x16_bf16(af, qf[kf], sT, 0, 0, 0);
  }
  if (MASK) {
#pragma unroll
    for (int r = 0; r < 16; r++) {
      int kvg = kvb + (r & 3) + 8 * (r >> 2) + 4 * h;
      if (kvg > qrow) sT[r] = 0.0f;  // multiplicative mask
    }
  }
  // row max: in-lane tree + permlane cross-half
  float tm[8];
#pragma unroll
  for (int r = 0; r < 8; r++) tm[r] = fmaxf(sT[r], sT[r + 8]);
#pragma unroll
  for (int r = 0; r < 4; r++) tm[r] = fmaxf(tm[r], tm[r + 4]);
  float mx = fmaxf(fmaxf(tm[0], tm[2]), fmaxf(tm[1], tm[3]));
  mx = xhalf_max(mx);
  // defer-max: rescale only when some row's max grew past m_run + 8 (P <= 2^8)
  if (!__all(mx <= m_run + 8.0f)) {
    float mnew = fmaxf(m_run, mx);
    float alpha = EXP2(m_run - mnew);
    m_run = mnew;
    l_run *= alpha;
    float ar[16];
#pragma unroll
    for (int r = 0; r < 16; r++)
      ar[r] = __shfl(alpha, (r & 3) + 8 * (r >> 2) + 4 * h);
#pragma unroll
    for (int nt = 0; nt < 4; nt++)
#pragma unroll
      for (int r = 0; r < 16; r++) acc[nt][r] *= ar[r];
  }
#pragma unroll
  for (int r = 0; r < 16; r++) sT[r] = EXP2(sT[r] - m_run);
  float ts[8];
#pragma unroll
  for (int r = 0; r < 8; r++) ts[r] = sT[r] + sT[r + 8];
#pragma unroll
  for (int r = 0; r < 4; r++) ts[r] = ts[r] + ts[r + 4];
  float sum = (ts[0] + ts[1]) + (ts[2] + ts[3]);
  sum = xhalf_sum(sum);
  l_run += sum;
  // pack P -> bf16 A-fragments: 2 permlane32_swap per 16-key group, then PV.
  // u[0] = {a0.lo | b0.lo}, u[2] = {a0.hi | b0.hi}  (R4-verified)
#pragma unroll
  for (int kl = 0; kl < 2; kl++) {
    const int ra = 8 * kl;
    const int rb = 8 * kl + 4;
    unsigned int a0 = cvtpk(sT[ra + 0], sT[ra + 1]);
    unsigned int a1 = cvtpk(sT[ra + 2], sT[ra + 3]);
    unsigned int b0 = cvtpk(sT[rb + 0], sT[rb + 1]);
    unsigned int b1 = cvtpk(sT[rb + 2], sT[rb + 3]);
    plswap(a0, b0);
    plswap(a1, b1);
    union { short8 v; unsigned int u[4]; } pa;
    pa.u[0] = a0; pa.u[1] = a1; pa.u[2] = b0; pa.u[3] = b1;
    const int vboff = 64 * kh + 32 * kl + 16 * h;
#pragma unroll
    for (int nt = 0; nt < 4; nt++) {
      short8 vb = ldV(cb + 16384, ln31 + 32 * nt, vboff);
      acc[nt] = __builtin_amdgcn_mfma_f32_32x32x16_bf16(pa.v, vb, acc[nt], 0, 0, 0);
    }
  }
}

// merge overlay: [2 qs][64 lanes] x 66 floats (stride 66 words: 2-way bank alias = free)
#define MSTRIDE 66

__global__ __launch_bounds__(256, 4) void attn_kernel(
    const float* __restrict__ Q, const unsigned short* __restrict__ Kb,
    const unsigned short* __restrict__ Vt, const float* __restrict__ SufV,
    float* __restrict__ out) {
  // single staging buffer (K @0: 16KB, V^T @16KB); merge overlay needs 33792B
  __shared__ __align__(16) char smem[2 * 64 * MSTRIDE * 4];

  const int tid = threadIdx.x;
  const int w = tid >> 6, lane = tid & 63;
  const int ln31 = lane & 31, h = lane >> 5;
  const int qs = w & 1;   // q half: rows [q0+32*qs, +32)
  const int kh = w >> 1;  // kv half of each 64-tile

  // LPT decode: longest strips (j=31) first; XCD x owns batches {2x, 2x+1}
  const int bid = blockIdx.x;
  const int x = bid & 7, r = bid >> 3;
  const int b = 2 * x + (r & 1);
  const int j = 31 - (r >> 1);

  const int q0 = j * 64;
  const int kv_end = q0 + 64;
  const int qrow = q0 + 32 * qs + ln31;

  // Q fragments (B-operand) from fp32, scale*log2e folded in:
  // frag kf element jj <-> d = 16*kf + 8*h + jj
  short8 qf[8];
  {
    const float* qsrc = Q + ((size_t)b * S_LEN + qrow) * D_DIM + 8 * h;
#pragma unroll
    for (int kf = 0; kf < 8; kf++) {
      float4 a = *reinterpret_cast<const float4*>(qsrc + 16 * kf);
      float4 c = *reinterpret_cast<const float4*>(qsrc + 16 * kf + 4);
      union { short8 v; unsigned int u[4]; } q8;
      q8.u[0] = cvtpk(a.x * QSC, a.y * QSC);
      q8.u[1] = cvtpk(a.z * QSC, a.w * QSC);
      q8.u[2] = cvtpk(c.x * QSC, c.y * QSC);
      q8.u[3] = cvtpk(c.z * QSC, c.w * QSC);
      qf[kf] = q8.v;
    }
  }

  f32x16 acc[4];
#pragma unroll
  for (int nt = 0; nt < 4; nt++)
#pragma unroll
    for (int rr = 0; rr < 16; rr++) acc[nt][rr] = 0.0f;
  float m_run = 0.0f, l_run = 0.0f;  // m starts at 0: masked zeros join the softmax

  // single-buffer loop: TLP (4 blocks/CU) hides the stage latency
  for (int kt = 0; kt <= j; kt++) {
    stage_tiles(smem, Kb, Vt, b, kt, w, lane);
    __syncthreads();  // drains vmcnt
    if (kt < j)
      tile_body<false>(smem, qf, acc, m_run, l_run, ln31, h, kh, qrow,
                       kt * 64 + 32 * kh);
    else
      tile_body<true>(smem, qf, acc, m_run, l_run, ln31, h, kh, qrow,
                      kt * 64 + 32 * kh);
    __syncthreads();  // buffer reuse (and merge overlay) safety
  }

  // merge kv halves (disjoint key sets) + masked-tail correction + write
  float* mb = (float*)smem;
  if (kh == 1) {
    float* p = mb + (size_t)(qs * 64 + lane) * MSTRIDE;
#pragma unroll
    for (int nt = 0; nt < 4; nt++)
#pragma unroll
      for (int rr = 0; rr < 16; rr++) p[nt * 16 + rr] = acc[nt][rr];
    p[64] = m_run;
    p[65] = l_run;
  }
  __syncthreads();
  if (kh == 0) {
    const float* p = mb + (size_t)(qs * 64 + lane) * MSTRIDE;
    float m1 = p[64], l1 = p[65];
    float m12 = fmaxf(m_run, m1);
    float b0 = EXP2(m_run - m12);
    float b1 = EXP2(m1 - m12);
    float l12 = l_run * b0 + l1 * b1;
    float e = EXP2(-m12);  // weight of each fully-masked (score 0) position
    l12 += (float)(S_LEN - kv_end) * e;
    float b0r[16], b1r[16], er[16], lr[16];
#pragma unroll
    for (int rr = 0; rr < 16; rr++) {
      int cr = (rr & 3) + 8 * (rr >> 2) + 4 * h;
      b0r[rr] = __shfl(b0, cr);
      b1r[rr] = __shfl(b1, cr);
      er[rr] = __shfl(e, cr);
      lr[rr] = __shfl(l12, cr);
    }
    const float* sv = SufV + ((size_t)b * 33 + (kv_end >> 6)) * 128;
    float* ob = out + ((size_t)b * S_LEN + q0 + 32 * qs) * D_DIM + ln31;
#pragma unroll
    for (int nt = 0; nt < 4; nt++) {
      float svv = sv[ln31 + 32 * nt];
#pragma unroll
      for (int rr = 0; rr < 16; rr++) {
        int cr = (rr & 3) + 8 * (rr >> 2) + 4 * h;
        float o = acc[nt][rr] * b0r[rr] + p[nt * 16 + rr] * b1r[rr] + er[rr] * svv;
        ob[(size_t)cr * D_DIM + 32 * nt] = o / lr[rr];
      }
    }
  }
}

// ---------------- launcher ----------------

extern "C" void kernel_launch(void* const* d_in, const int* in_sizes, int n_in,
                              void* d_out, int out_size, void* d_ws, size_t ws_size,
                              hipStream_t stream) {
  const float* Q = (const float*)d_in[0];
  const float* K = (const float*)d_in[1];
  const float* V = (const float*)d_in[2];
  float* out = (float*)d_out;

  char* ws = (char*)d_ws;
  unsigned short* Kb = (unsigned short*)ws;                 // 8 MiB
  unsigned short* Vt = Kb + 4194304;                        // 8 MiB
  float* Tsum = (float*)(ws + 16777216);                    // 256 KiB
  float* SufV = Tsum + 65536;                               // 264 KiB

  prep<<<3072, 256, 0, stream>>>(K, V, Kb, Vt, Tsum);
  sufB<<<16, 128, 0, stream>>>(Tsum, SufV);
  attn_kernel<<<512, 256, 0, stream>>>(Q, Kb, Vt, SufV, out);
}

// Round 6
// 143.531 us; speedup vs baseline: 2.7321x; 2.7321x over previous
//
#include <hip/hip_runtime.h>
#include <hip/hip_bf16.h>

#define DEVI static __device__ __forceinline__

typedef __attribute__((ext_vector_type(8))) short short8;
typedef __attribute__((ext_vector_type(16))) float f32x16;
typedef __attribute__((ext_vector_type(2))) unsigned int uintx2;

#define S_LEN 2048
#define D_DIM 128
#define NBATCH 16
// (1/sqrt(128)) * log2(e): base-2 softmax, scale folded into Q conversion
#define QSC ((float)(0.08838834764831845 * 1.4426950408889634))

#if __has_builtin(__builtin_amdgcn_exp2f)
#define EXP2(x) __builtin_amdgcn_exp2f(x)
#else
#define EXP2(x) exp2f(x)
#endif

DEVI unsigned short f2bf(float x) {
  union { float f; unsigned int u; } a; a.f = x;
  unsigned int u = a.u;
  unsigned int r = (u + 0x7fffu + ((u >> 16) & 1u)) >> 16;
  return (unsigned short)r;
}

DEVI unsigned int cvtpk(float lo, float hi) {
  unsigned int r;
  asm volatile("v_cvt_pk_bf16_f32 %0, %1, %2" : "=v"(r) : "v"(lo), "v"(hi));
  return r;
}

// v_permlane32_swap_b32: swaps UPPER half of first arg with LOWER half of second.
// post: a = {a.lo | b.lo}, b = {a.hi | b.hi}   (verified R4)
DEVI void plswap(unsigned int& a, unsigned int& b) {
  uintx2 r = __builtin_amdgcn_permlane32_swap(a, b, false, false);
  a = r[0];
  b = r[1];
}

DEVI float xhalf_max(float x) {
  union { float f; unsigned int u; } a, b;
  a.f = x; b.f = x;
  plswap(a.u, b.u);
  return fmaxf(a.f, b.f);
}

DEVI float xhalf_sum(float x) {
  union { float f; unsigned int u; } a, b;
  a.f = x; b.f = x;
  plswap(a.u, b.u);
  return a.f + b.f;
}

// ---------------- prepass ----------------

// blocks [0,1024): V [b][s][d] fp32 -> Vt [b][d][s] bf16 + per-64-row tile sums
// blocks [1024,3072): K fp32 -> bf16
__global__ void prep(const float* __restrict__ K, const float* __restrict__ V,
                     unsigned short* __restrict__ Kb, unsigned short* __restrict__ Vt,
                     float* __restrict__ Tsum) {
  __shared__ unsigned short t[64][68];
  const int tt = threadIdx.x;
  if (blockIdx.x >= 1024) {
    const int M4 = (NBATCH * S_LEN * D_DIM) / 4;
    for (int i = (blockIdx.x - 1024) * 256 + tt; i < M4; i += 2048 * 256) {
      const size_t idx = (size_t)i * 4;
      const float4 v = *reinterpret_cast<const float4*>(K + idx);
      ushort4 o;
      o.x = f2bf(v.x); o.y = f2bf(v.y); o.z = f2bf(v.z); o.w = f2bf(v.w);
      *reinterpret_cast<ushort4*>(Kb + idx) = o;
    }
    return;
  }
  const int bid = blockIdx.x;
  const int b = bid >> 6, rem = bid & 63;
  const int st = rem & 31, s0 = st * 64, d0 = (rem >> 5) * 64;
  const int r = tt >> 2, c = (tt & 3) * 16;
  const float* src = V + ((size_t)(b * S_LEN + s0 + r)) * D_DIM + d0 + c;
#pragma unroll
  for (int i = 0; i < 4; i++) {
    float4 v = reinterpret_cast<const float4*>(src)[i];
    t[r][c + 4 * i + 0] = f2bf(v.x);
    t[r][c + 4 * i + 1] = f2bf(v.y);
    t[r][c + 4 * i + 2] = f2bf(v.z);
    t[r][c + 4 * i + 3] = f2bf(v.w);
  }
  __syncthreads();
  unsigned short* dst = Vt + ((size_t)(b * D_DIM + d0 + r)) * S_LEN + s0 + c;
#pragma unroll
  for (int i = 0; i < 4; i++) {
    ushort4 o;
    o.x = t[c + 4 * i + 0][r];
    o.y = t[c + 4 * i + 1][r];
    o.z = t[c + 4 * i + 2][r];
    o.w = t[c + 4 * i + 3][r];
    reinterpret_cast<ushort4*>(dst)[i] = o;
  }
  if (tt < 64) {
    float s = 0.0f;
#pragma unroll 8
    for (int rr = 0; rr < 64; rr++) {
      union { float f; unsigned int u; } cv;
      cv.u = ((unsigned int)t[rr][tt]) << 16;
      s += cv.f;
    }
    Tsum[((size_t)b * 32 + st) * 128 + d0 + tt] = s;
  }
}

// SufV[b][t][d] = sum_{t' >= t} Tsum[b][t'][d]; SufV[b][32][d] = 0
__global__ void sufB(const float* __restrict__ Tsum, float* __restrict__ SufV) {
  const int b = blockIdx.x;
  const int d = threadIdx.x;
  float v[32];
#pragma unroll
  for (int t = 0; t < 32; t++) v[t] = Tsum[((size_t)b * 32 + t) * 128 + d];
  float run = 0.0f;
  SufV[((size_t)b * 33 + 32) * 128 + d] = 0.0f;
#pragma unroll
  for (int t = 31; t >= 0; t--) {
    run += v[t];
    SufV[((size_t)b * 33 + t) * 128 + d] = run;
  }
}

// ---------------- attention kernel ----------------

// 8 waves: waves 0..3 stage K (16 chunks of 1KB), waves 4..7 stage V^T
DEVI void stage_tiles(char* ldsbuf, const unsigned short* Kb,
                      const unsigned short* Vt, int b, int kt, int w, int lane) {
  const int kv0 = kt * 64;
  if (w < 4) {
    // K tile: 64 rows x 256B contiguous; XOR-swizzle (16 slots) via pre-swizzled source
    const char* ktile = (const char*)(Kb + ((size_t)b * S_LEN + kv0) * D_DIM);
#pragma unroll
    for (int i = 0; i < 4; i++) {
      int c = w * 4 + i;
      int L = c * 1024 + lane * 16;
      int row = L >> 8;
      int src = row * 256 + ((L & 255) ^ ((row & 15) << 4));
      __builtin_amdgcn_global_load_lds(
          (const __attribute__((address_space(1))) unsigned int*)(ktile + src),
          (__attribute__((address_space(3))) unsigned int*)(ldsbuf + c * 1024),
          16, 0, 0);
    }
  } else {
    // V^T tile: 128 rows x 128B, row stride S*2 in global
    char* ldsV = ldsbuf + 16384;
#pragma unroll
    for (int i = 0; i < 4; i++) {
      int c = (w - 4) * 4 + i;
      int L = c * 1024 + lane * 16;
      int row = L >> 7;
      int xs = (L & 127) ^ ((row & 7) << 4);
      const char* src = (const char*)Vt +
                        (((size_t)b * D_DIM + row) * S_LEN + kv0) * 2 + xs;
      __builtin_amdgcn_global_load_lds(
          (const __attribute__((address_space(1))) unsigned int*)src,
          (__attribute__((address_space(3))) unsigned int*)(ldsV + c * 1024),
          16, 0, 0);
    }
  }
}

DEVI short8 ldK(const char* ldsK, int row, int off) {
  int addr = row * 256 + (off ^ ((row & 15) << 4));
  return *reinterpret_cast<const short8*>(ldsK + addr);
}
DEVI short8 ldV(const char* ldsV, int row, int off) {
  int addr = row * 128 + (off ^ ((row & 7) << 4));
  return *reinterpret_cast<const short8*>(ldsV + addr);
}

template <bool MASK>
DEVI void tile_body(const char* cb, const short8* qf, f32x16& acc0, f32x16& acc1,
                    float& m_run, float& l_run, const int ln31, const int h,
                    const int kh, const int dh, const int qrow, const int kvb) {
  // S^T = K_half * Q^T  (swapped operands: lane owns one q column)
  f32x16 sT;
#pragma unroll
  for (int r = 0; r < 16; r++) sT[r] = 0.0f;
#pragma unroll
  for (int kf = 0; kf < 8; kf++) {
    short8 af = ldK(cb, ln31 + 32 * kh, 32 * kf + 16 * h);
    sT = __builtin_amdgcn_mfma_f32_32x32x16_bf16(af, qf[kf], sT, 0, 0, 0);
  }
  if (MASK) {
#pragma unroll
    for (int r = 0; r < 16; r++) {
      int kvg = kvb + (r & 3) + 8 * (r >> 2) + 4 * h;
      if (kvg > qrow) sT[r] = 0.0f;  // multiplicative mask
    }
  }
  // row max: in-lane tree + permlane cross-half
  float tm[8];
#pragma unroll
  for (int r = 0; r < 8; r++) tm[r] = fmaxf(sT[r], sT[r + 8]);
#pragma unroll
  for (int r = 0; r < 4; r++) tm[r] = fmaxf(tm[r], tm[r + 4]);
  float mx = fmaxf(fmaxf(tm[0], tm[2]), fmaxf(tm[1], tm[3]));
  mx = xhalf_max(mx);
  // defer-max: rescale only when some row's max grew past m_run + 8 (P <= 2^8)
  if (!__all(mx <= m_run + 8.0f)) {
    float mnew = fmaxf(m_run, mx);
    float alpha = EXP2(m_run - mnew);
    m_run = mnew;
    l_run *= alpha;
    float ar[16];
#pragma unroll
    for (int r = 0; r < 16; r++)
      ar[r] = __shfl(alpha, (r & 3) + 8 * (r >> 2) + 4 * h);
#pragma unroll
    for (int r = 0; r < 16; r++) acc0[r] *= ar[r];
#pragma unroll
    for (int r = 0; r < 16; r++) acc1[r] *= ar[r];
  }
#pragma unroll
  for (int r = 0; r < 16; r++) sT[r] = EXP2(sT[r] - m_run);
  float ts[8];
#pragma unroll
  for (int r = 0; r < 8; r++) ts[r] = sT[r] + sT[r + 8];
#pragma unroll
  for (int r = 0; r < 4; r++) ts[r] = ts[r] + ts[r + 4];
  float sum = (ts[0] + ts[1]) + (ts[2] + ts[3]);
  sum = xhalf_sum(sum);
  l_run += sum;
  // pack P -> bf16 A-fragments: 2 permlane32_swap per 16-key group, then PV.
  // u[0] = {a0.lo | b0.lo}, u[2] = {a0.hi | b0.hi}  (R4-verified)
#pragma unroll
  for (int kl = 0; kl < 2; kl++) {
    const int ra = 8 * kl;
    const int rb = 8 * kl + 4;
    unsigned int a0 = cvtpk(sT[ra + 0], sT[ra + 1]);
    unsigned int a1 = cvtpk(sT[ra + 2], sT[ra + 3]);
    unsigned int b0 = cvtpk(sT[rb + 0], sT[rb + 1]);
    unsigned int b1 = cvtpk(sT[rb + 2], sT[rb + 3]);
    plswap(a0, b0);
    plswap(a1, b1);
    union { short8 v; unsigned int u[4]; } pa;
    pa.u[0] = a0; pa.u[1] = a1; pa.u[2] = b0; pa.u[3] = b1;
    const int vboff = 64 * kh + 32 * kl + 16 * h;
    {
      short8 vb = ldV(cb + 16384, ln31 + 32 * (2 * dh + 0), vboff);
      acc0 = __builtin_amdgcn_mfma_f32_32x32x16_bf16(pa.v, vb, acc0, 0, 0, 0);
    }
    {
      short8 vb = ldV(cb + 16384, ln31 + 32 * (2 * dh + 1), vboff);
      acc1 = __builtin_amdgcn_mfma_f32_32x32x16_bf16(pa.v, vb, acc1, 0, 0, 0);
    }
  }
}

// merge overlay: [4 groups (qs*2+dh)][64 lanes] x 35 floats (stride 35: 2-way alias = free)
#define MSTRIDE 35

__global__ __launch_bounds__(512, 4) void attn_kernel(
    const float* __restrict__ Q, const unsigned short* __restrict__ Kb,
    const unsigned short* __restrict__ Vt, const float* __restrict__ SufV,
    float* __restrict__ out) {
  // double-buffered staging (per buf: K @0 16KB, V^T @16KB); overlay reuses post-loop
  __shared__ __align__(16) char smem[2 * 32768];

  const int tid = threadIdx.x;
  const int w = tid >> 6, lane = tid & 63;
  const int ln31 = lane & 31, h = lane >> 5;
  const int qs = w & 1;        // q half: rows [q0+32*qs, +32)
  const int kh = (w >> 1) & 1; // kv half of each 64-tile
  const int dh = w >> 2;       // d half: output col tiles {2dh, 2dh+1}

  // balanced-pair decode: CU gets strips j and 31-j (33 tiles total); long first.
  // XCD x owns batches {2x, 2x+1}.
  const int bid = blockIdx.x;
  const int x = bid & 7, s = bid >> 3;
  const int b = 2 * x + (s & 1);
  const int j = (s < 32) ? (31 - (s >> 1)) : ((s >> 1) - 16);

  const int q0 = j * 64;
  const int kv_end = q0 + 64;
  const int qrow = q0 + 32 * qs + ln31;

  // Q fragments (B-operand) from fp32, scale*log2e folded in:
  // frag kf element jj <-> d = 16*kf + 8*h + jj
  short8 qf[8];
  {
    const float* qsrc = Q + ((size_t)b * S_LEN + qrow) * D_DIM + 8 * h;
#pragma unroll
    for (int kf = 0; kf < 8; kf++) {
      float4 a = *reinterpret_cast<const float4*>(qsrc + 16 * kf);
      float4 c = *reinterpret_cast<const float4*>(qsrc + 16 * kf + 4);
      union { short8 v; unsigned int u[4]; } q8;
      q8.u[0] = cvtpk(a.x * QSC, a.y * QSC);
      q8.u[1] = cvtpk(a.z * QSC, a.w * QSC);
      q8.u[2] = cvtpk(c.x * QSC, c.y * QSC);
      q8.u[3] = cvtpk(c.z * QSC, c.w * QSC);
      qf[kf] = q8.v;
    }
  }

  f32x16 acc0, acc1;
#pragma unroll
  for (int rr = 0; rr < 16; rr++) { acc0[rr] = 0.0f; acc1[rr] = 0.0f; }
  float m_run = 0.0f, l_run = 0.0f;  // m starts at 0: masked zeros join the softmax

  stage_tiles(smem, Kb, Vt, b, 0, w, lane);
  __syncthreads();
  int cur = 0;
  for (int kt = 0; kt <= j; kt++) {
    char* cb = smem + (size_t)cur * 32768;
    const int nxt = cur ^ 1;
    if (kt < j) {
      stage_tiles(smem + (size_t)nxt * 32768, Kb, Vt, b, kt + 1, w, lane);
      tile_body<false>(cb, qf, acc0, acc1, m_run, l_run, ln31, h, kh, dh, qrow,
                       kt * 64 + 32 * kh);
    } else {
      tile_body<true>(cb, qf, acc0, acc1, m_run, l_run, ln31, h, kh, dh, qrow,
                      kt * 64 + 32 * kh);
    }
    __syncthreads();
    cur = nxt;
  }

  // merge kv halves (disjoint key sets) + masked-tail correction + write
  float* mb = (float*)smem;
  const int g = qs * 2 + dh;
  if (kh == 1) {
    float* p = mb + (size_t)(g * 64 + lane) * MSTRIDE;
#pragma unroll
    for (int rr = 0; rr < 16; rr++) p[rr] = acc0[rr];
#pragma unroll
    for (int rr = 0; rr < 16; rr++) p[16 + rr] = acc1[rr];
    p[32] = m_run;
    p[33] = l_run;
  }
  __syncthreads();
  if (kh == 0) {
    const float* p = mb + (size_t)(g * 64 + lane) * MSTRIDE;
    float m1 = p[32], l1 = p[33];
    float m12 = fmaxf(m_run, m1);
    float b0 = EXP2(m_run - m12);
    float b1 = EXP2(m1 - m12);
    float l12 = l_run * b0 + l1 * b1;
    float e = EXP2(-m12);  // weight of each fully-masked (score 0) position
    l12 += (float)(S_LEN - kv_end) * e;
    const float* sv = SufV + ((size_t)b * 33 + (kv_end >> 6)) * 128;
    const float sv0 = sv[ln31 + 32 * (2 * dh + 0)];
    const float sv1 = sv[ln31 + 32 * (2 * dh + 1)];
    float* ob = out + ((size_t)b * S_LEN + q0 + 32 * qs) * D_DIM + ln31;
#pragma unroll
    for (int rr = 0; rr < 16; rr++) {
      int cr = (rr & 3) + 8 * (rr >> 2) + 4 * h;
      float b0c = __shfl(b0, cr);
      float b1c = __shfl(b1, cr);
      float ec = __shfl(e, cr);
      float lc = __shfl(l12, cr);
      float o0 = acc0[rr] * b0c + p[rr] * b1c + ec * sv0;
      float o1 = acc1[rr] * b0c + p[16 + rr] * b1c + ec * sv1;
      ob[(size_t)cr * D_DIM + 32 * (2 * dh + 0)] = o0 / lc;
      ob[(size_t)cr * D_DIM + 32 * (2 * dh + 1)] = o1 / lc;
    }
  }
}

// ---------------- launcher ----------------

extern "C" void kernel_launch(void* const* d_in, const int* in_sizes, int n_in,
                              void* d_out, int out_size, void* d_ws, size_t ws_size,
                              hipStream_t stream) {
  const float* Q = (const float*)d_in[0];
  const float* K = (const float*)d_in[1];
  const float* V = (const float*)d_in[2];
  float* out = (float*)d_out;

  char* ws = (char*)d_ws;
  unsigned short* Kb = (unsigned short*)ws;                 // 8 MiB
  unsigned short* Vt = Kb + 4194304;                        // 8 MiB
  float* Tsum = (float*)(ws + 16777216);                    // 256 KiB
  float* SufV = Tsum + 65536;                               // 264 KiB

  prep<<<3072, 256, 0, stream>>>(K, V, Kb, Vt, Tsum);
  sufB<<<16, 128, 0, stream>>>(Tsum, SufV);
  attn_kernel<<<512, 512, 0, stream>>>(Q, Kb, Vt, SufV, out);
}

// Round 8
// 69.007 us; speedup vs baseline: 5.6826x; 2.0799x over previous
//
#include <hip/hip_runtime.h>
#include <hip/hip_bf16.h>

#define DEVI static __device__ __forceinline__

typedef __attribute__((ext_vector_type(8))) short short8;
typedef __attribute__((ext_vector_type(16))) float f32x16;
typedef __attribute__((ext_vector_type(2))) unsigned int uintx2;

#define S_LEN 2048
#define D_DIM 128
#define NBATCH 16
// (1/sqrt(128)) * log2(e): base-2 softmax, scale folded into Q conversion
#define QSC ((float)(0.08838834764831845 * 1.4426950408889634))

#if __has_builtin(__builtin_amdgcn_exp2f)
#define EXP2(x) __builtin_amdgcn_exp2f(x)
#else
#define EXP2(x) exp2f(x)
#endif

DEVI unsigned short f2bf(float x) {
  union { float f; unsigned int u; } a; a.f = x;
  unsigned int u = a.u;
  unsigned int r = (u + 0x7fffu + ((u >> 16) & 1u)) >> 16;
  return (unsigned short)r;
}

DEVI unsigned int cvtpk(float lo, float hi) {
  unsigned int r;
  asm volatile("v_cvt_pk_bf16_f32 %0, %1, %2" : "=v"(r) : "v"(lo), "v"(hi));
  return r;
}

// v_permlane32_swap_b32: post: a = {a.lo | b.lo}, b = {a.hi | b.hi}  (R4-verified)
DEVI void plswap(unsigned int& a, unsigned int& b) {
  uintx2 r = __builtin_amdgcn_permlane32_swap(a, b, false, false);
  a = r[0];
  b = r[1];
}

DEVI float xhalf_max(float x) {
  union { float f; unsigned int u; } a, b;
  a.f = x; b.f = x;
  plswap(a.u, b.u);
  return fmaxf(a.f, b.f);
}

DEVI float xhalf_sum(float x) {
  union { float f; unsigned int u; } a, b;
  a.f = x; b.f = x;
  plswap(a.u, b.u);
  return a.f + b.f;
}

// ---------------- prepass ----------------

// blocks [0,1024): V [b][s][d] fp32 -> Vt TILE-MAJOR [b][kt][d 0..127][64 keys] bf16
//                  + per-64-row tile sums
// blocks [1024,3072): K fp32 -> bf16 (row-major unchanged)
__global__ void prep(const float* __restrict__ K, const float* __restrict__ V,
                     unsigned short* __restrict__ Kb, unsigned short* __restrict__ Vt,
                     float* __restrict__ Tsum) {
  __shared__ unsigned short t[64][68];
  const int tt = threadIdx.x;
  if (blockIdx.x >= 1024) {
    const int M4 = (NBATCH * S_LEN * D_DIM) / 4;
    for (int i = (blockIdx.x - 1024) * 256 + tt; i < M4; i += 2048 * 256) {
      const size_t idx = (size_t)i * 4;
      const float4 v = *reinterpret_cast<const float4*>(K + idx);
      ushort4 o;
      o.x = f2bf(v.x); o.y = f2bf(v.y); o.z = f2bf(v.z); o.w = f2bf(v.w);
      *reinterpret_cast<ushort4*>(Kb + idx) = o;
    }
    return;
  }
  const int bid = blockIdx.x;
  const int b = bid >> 6, rem = bid & 63;
  const int st = rem & 31, s0 = st * 64, d0 = (rem >> 5) * 64;
  const int r = tt >> 2, c = (tt & 3) * 16;
  const float* src = V + ((size_t)(b * S_LEN + s0 + r)) * D_DIM + d0 + c;
#pragma unroll
  for (int i = 0; i < 4; i++) {
    float4 v = reinterpret_cast<const float4*>(src)[i];
    t[r][c + 4 * i + 0] = f2bf(v.x);
    t[r][c + 4 * i + 1] = f2bf(v.y);
    t[r][c + 4 * i + 2] = f2bf(v.z);
    t[r][c + 4 * i + 3] = f2bf(v.w);
  }
  __syncthreads();
  // tile-major: Vt[((b*32+st)*128 + d)*64 + key]
  unsigned short* dst = Vt + (((size_t)(b * 32 + st)) * 128 + d0 + r) * 64 + c;
#pragma unroll
  for (int i = 0; i < 4; i++) {
    ushort4 o;
    o.x = t[c + 4 * i + 0][r];
    o.y = t[c + 4 * i + 1][r];
    o.z = t[c + 4 * i + 2][r];
    o.w = t[c + 4 * i + 3][r];
    reinterpret_cast<ushort4*>(dst)[i] = o;
  }
  if (tt < 64) {
    float s = 0.0f;
#pragma unroll 8
    for (int rr = 0; rr < 64; rr++) {
      union { float f; unsigned int u; } cv;
      cv.u = ((unsigned int)t[rr][tt]) << 16;
      s += cv.f;
    }
    Tsum[((size_t)b * 32 + st) * 128 + d0 + tt] = s;
  }
}

// SufV[b][t][d] = sum_{t' >= t} Tsum[b][t'][d]; SufV[b][32][d] = 0
__global__ void sufB(const float* __restrict__ Tsum, float* __restrict__ SufV) {
  const int b = blockIdx.x;
  const int d = threadIdx.x;
  float v[32];
#pragma unroll
  for (int t = 0; t < 32; t++) v[t] = Tsum[((size_t)b * 32 + t) * 128 + d];
  float run = 0.0f;
  SufV[((size_t)b * 33 + 32) * 128 + d] = 0.0f;
#pragma unroll
  for (int t = 31; t >= 0; t--) {
    run += v[t];
    SufV[((size_t)b * 33 + t) * 128 + d] = run;
  }
}

// ---------------- attention kernel ----------------

#define AS1 __attribute__((address_space(1)))
#define AS3 __attribute__((address_space(3)))

// wave 0 stages K tile (16KB contiguous) -> LDS [0,16K)
// wave 1 stages V tile (16KB contiguous, tile-major) -> LDS [16K,32K)
// imm = 0 always (R7 lesson: 13-bit signed imm, and swizzle fold periods exceed it)
DEVI void stage(char* smem, const char* tileK, const char* tileV, int w, int lane) {
  if (w == 0) {
#pragma unroll
    for (int c = 0; c < 16; c++) {
      int L = c * 1024 + lane * 16;
      int row = L >> 8;
      const char* src = tileK + row * 256 + ((L & 255) ^ ((row & 15) << 4));
      __builtin_amdgcn_global_load_lds((const AS1 unsigned int*)src,
                                       (AS3 unsigned int*)(smem + c * 1024), 16, 0, 0);
    }
  } else {
#pragma unroll
    for (int c = 0; c < 16; c++) {
      int L = c * 1024 + lane * 16;
      int row = L >> 7;
      const char* src = tileV + (L & ~127) + ((L & 127) ^ ((row & 7) << 4));
      __builtin_amdgcn_global_load_lds((const AS1 unsigned int*)src,
                                       (AS3 unsigned int*)(smem + 16384 + c * 1024),
                                       16, 0, 0);
    }
  }
}

DEVI short8 ldK(const char* ldsK, int row, int off) {
  int addr = row * 256 + (off ^ ((row & 15) << 4));
  return *reinterpret_cast<const short8*>(ldsK + addr);
}
DEVI short8 ldV(const char* ldsV, int row, int off) {
  int addr = row * 128 + (off ^ ((row & 7) << 4));
  return *reinterpret_cast<const short8*>(ldsV + addr);
}

template <bool MASK>
DEVI void tile_body(const char* cb, const short8* qf, f32x16 (&acc)[4],
                    float& m_run, float& l_run, const int ln31, const int h,
                    const int kh, const int qrow, const int kvb) {
  // S^T = K_half * Q^T  (swapped operands: lane owns one q column)
  f32x16 sT;
#pragma unroll
  for (int r = 0; r < 16; r++) sT[r] = 0.0f;
  __builtin_amdgcn_s_setprio(1);
#pragma unroll
  for (int kf = 0; kf < 8; kf++) {
    short8 af = ldK(cb, ln31 + 32 * kh, 32 * kf + 16 * h);
    sT = __builtin_amdgcn_mfma_f32_32x32x16_bf16(af, qf[kf], sT, 0, 0, 0);
  }
  __builtin_amdgcn_s_setprio(0);
  if (MASK) {
#pragma unroll
    for (int r = 0; r < 16; r++) {
      int kvg = kvb + (r & 3) + 8 * (r >> 2) + 4 * h;
      if (kvg > qrow) sT[r] = 0.0f;  // multiplicative mask
    }
  }
  // row max: in-lane tree + permlane cross-half
  float tm[8];
#pragma unroll
  for (int r = 0; r < 8; r++) tm[r] = fmaxf(sT[r], sT[r + 8]);
#pragma unroll
  for (int r = 0; r < 4; r++) tm[r] = fmaxf(tm[r], tm[r + 4]);
  float mx = fmaxf(fmaxf(tm[0], tm[2]), fmaxf(tm[1], tm[3]));
  mx = xhalf_max(mx);
  // defer-max: rescale only when some row's max grew past m_run + 8 (P <= 2^8)
  if (!__all(mx <= m_run + 8.0f)) {
    float mnew = fmaxf(m_run, mx);
    float alpha = EXP2(m_run - mnew);
    m_run = mnew;
    l_run *= alpha;
    float ar[16];
#pragma unroll
    for (int r = 0; r < 16; r++)
      ar[r] = __shfl(alpha, (r & 3) + 8 * (r >> 2) + 4 * h);
#pragma unroll
    for (int nt = 0; nt < 4; nt++)
#pragma unroll
      for (int r = 0; r < 16; r++) acc[nt][r] *= ar[r];
  }
#pragma unroll
  for (int r = 0; r < 16; r++) sT[r] = EXP2(sT[r] - m_run);
  float ts[8];
#pragma unroll
  for (int r = 0; r < 8; r++) ts[r] = sT[r] + sT[r + 8];
#pragma unroll
  for (int r = 0; r < 4; r++) ts[r] = ts[r] + ts[r + 4];
  float sum = (ts[0] + ts[1]) + (ts[2] + ts[3]);
  sum = xhalf_sum(sum);
  l_run += sum;
  // pack P -> bf16 A-fragments: u[0]={a.lo|b.lo}, u[2]={a.hi|b.hi} (R4-verified)
#pragma unroll
  for (int kl = 0; kl < 2; kl++) {
    const int ra = 8 * kl;
    const int rb = 8 * kl + 4;
    unsigned int a0 = cvtpk(sT[ra + 0], sT[ra + 1]);
    unsigned int a1 = cvtpk(sT[ra + 2], sT[ra + 3]);
    unsigned int b0 = cvtpk(sT[rb + 0], sT[rb + 1]);
    unsigned int b1 = cvtpk(sT[rb + 2], sT[rb + 3]);
    plswap(a0, b0);
    plswap(a1, b1);
    union { short8 v; unsigned int u[4]; } pa;
    pa.u[0] = a0; pa.u[1] = a1; pa.u[2] = b0; pa.u[3] = b1;
    const int vboff = 64 * kh + 32 * kl + 16 * h;
    __builtin_amdgcn_s_setprio(1);
#pragma unroll
    for (int nt = 0; nt < 4; nt++) {
      short8 vb = ldV(cb + 16384, ln31 + 32 * nt, vboff);
      acc[nt] = __builtin_amdgcn_mfma_f32_32x32x16_bf16(pa.v, vb, acc[nt], 0, 0, 0);
    }
    __builtin_amdgcn_s_setprio(0);
  }
}

// merge overlay: [64 lanes] x 67 floats (odd stride -> conflict-light)
#define MSTRIDE 67

__global__ __launch_bounds__(128, 2) void attn_kernel(
    const float* __restrict__ Q, const unsigned short* __restrict__ Kb,
    const unsigned short* __restrict__ Vt, const float* __restrict__ SufV,
    float* __restrict__ out) {
  __shared__ __align__(16) char smem[32768];  // K @0 16KB, V @16KB; overlay post-loop

  const int tid = threadIdx.x;
  const int w = tid >> 6, lane = tid & 63;  // w == kh (kv half)
  const int ln31 = lane & 31, h = lane >> 5;
  const int kh = w;

  // LPT decode: 1024 blocks; long strips (j=31) first.
  // bid = g*32 + qs*16 + pb*8 + x ; XCD x owns batches {2x, 2x+1}
  const int bid = blockIdx.x;
  const int x = bid & 7;
  const int pb = (bid >> 3) & 1;
  const int qs = (bid >> 4) & 1;
  const int g = bid >> 5;
  const int b = 2 * x + pb;
  const int j = 31 - g;

  const int q0 = j * 64;
  const int kv_end = q0 + 64;
  const int qrow = q0 + 32 * qs + ln31;

  // Q fragments (B-operand) from fp32, scale*log2e folded in:
  // frag kf element jj <-> d = 16*kf + 8*h + jj
  short8 qf[8];
  {
    const float* qsrc = Q + ((size_t)b * S_LEN + qrow) * D_DIM + 8 * h;
#pragma unroll
    for (int kf = 0; kf < 8; kf++) {
      float4 a = *reinterpret_cast<const float4*>(qsrc + 16 * kf);
      float4 c = *reinterpret_cast<const float4*>(qsrc + 16 * kf + 4);
      union { short8 v; unsigned int u[4]; } q8;
      q8.u[0] = cvtpk(a.x * QSC, a.y * QSC);
      q8.u[1] = cvtpk(a.z * QSC, a.w * QSC);
      q8.u[2] = cvtpk(c.x * QSC, c.y * QSC);
      q8.u[3] = cvtpk(c.z * QSC, c.w * QSC);
      qf[kf] = q8.v;
    }
  }

  // staging tile bases (both contiguous 16KB per kv-tile; Vt is tile-major)
  const char* tk = (const char*)(Kb + (size_t)b * S_LEN * D_DIM);
  const char* tv = (const char*)Vt + (size_t)b * (S_LEN * D_DIM * 2);

  f32x16 acc[4];
#pragma unroll
  for (int nt = 0; nt < 4; nt++)
#pragma unroll
    for (int rr = 0; rr < 16; rr++) acc[nt][rr] = 0.0f;
  float m_run = 0.0f, l_run = 0.0f;  // m starts at 0: masked zeros join the softmax

  for (int kt = 0; kt <= j; kt++) {
    stage(smem, tk, tv, w, lane);
    tk += 16384; tv += 16384;
    __syncthreads();  // compiler drains vmcnt before barrier -> tile ready
    if (kt < j)
      tile_body<false>(smem, qf, acc, m_run, l_run, ln31, h, kh, qrow,
                       kt * 64 + 32 * kh);
    else
      tile_body<true>(smem, qf, acc, m_run, l_run, ln31, h, kh, qrow,
                      kt * 64 + 32 * kh);
    __syncthreads();  // buffer reuse safety
  }

  // merge kv halves (disjoint key sets) + masked-tail correction + write
  float* mb = (float*)smem;
  if (kh == 1) {
    float* p = mb + (size_t)lane * MSTRIDE;
#pragma unroll
    for (int nt = 0; nt < 4; nt++)
#pragma unroll
      for (int rr = 0; rr < 16; rr++) p[nt * 16 + rr] = acc[nt][rr];
    p[64] = m_run;
    p[65] = l_run;
  }
  __syncthreads();
  if (kh == 0) {
    const float* p = mb + (size_t)lane * MSTRIDE;
    float m1 = p[64], l1 = p[65];
    float m12 = fmaxf(m_run, m1);
    float b0 = EXP2(m_run - m12);
    float b1 = EXP2(m1 - m12);
    float l12 = l_run * b0 + l1 * b1;
    float e = EXP2(-m12);  // weight of each fully-masked (score 0) position
    l12 += (float)(S_LEN - kv_end) * e;
    float b0r[16], b1r[16], er[16], lr[16];
#pragma unroll
    for (int rr = 0; rr < 16; rr++) {
      int cr = (rr & 3) + 8 * (rr >> 2) + 4 * h;
      b0r[rr] = __shfl(b0, cr);
      b1r[rr] = __shfl(b1, cr);
      er[rr] = __shfl(e, cr);
      lr[rr] = __shfl(l12, cr);
    }
    const float* sv = SufV + ((size_t)b * 33 + (kv_end >> 6)) * 128;
    float* ob = out + ((size_t)b * S_LEN + q0 + 32 * qs) * D_DIM + ln31;
#pragma unroll
    for (int nt = 0; nt < 4; nt++) {
      float svv = sv[ln31 + 32 * nt];
#pragma unroll
      for (int rr = 0; rr < 16; rr++) {
        int cr = (rr & 3) + 8 * (rr >> 2) + 4 * h;
        float o = acc[nt][rr] * b0r[rr] + p[nt * 16 + rr] * b1r[rr] + er[rr] * svv;
        ob[(size_t)cr * D_DIM + 32 * nt] = o / lr[rr];
      }
    }
  }
}

// ---------------- launcher ----------------

extern "C" void kernel_launch(void* const* d_in, const int* in_sizes, int n_in,
                              void* d_out, int out_size, void* d_ws, size_t ws_size,
                              hipStream_t stream) {
  const float* Q = (const float*)d_in[0];
  const float* K = (const float*)d_in[1];
  const float* V = (const float*)d_in[2];
  float* out = (float*)d_out;

  char* ws = (char*)d_ws;
  unsigned short* Kb = (unsigned short*)ws;                 // 8 MiB
  unsigned short* Vt = Kb + 4194304;                        // 8 MiB (tile-major)
  float* Tsum = (float*)(ws + 16777216);                    // 256 KiB
  float* SufV = Tsum + 65536;                               // 264 KiB

  prep<<<3072, 256, 0, stream>>>(K, V, Kb, Vt, Tsum);
  sufB<<<16, 128, 0, stream>>>(Tsum, SufV);
  attn_kernel<<<1024, 128, 0, stream>>>(Q, Kb, Vt, SufV, out);
}

// Round 9
// 53.118 us; speedup vs baseline: 7.3823x; 1.2991x over previous
//
#include <hip/hip_runtime.h>
#include <hip/hip_bf16.h>

#define DEVI static __device__ __forceinline__

typedef __attribute__((ext_vector_type(8))) short short8;
typedef __attribute__((ext_vector_type(16))) float f32x16;
typedef __attribute__((ext_vector_type(2))) unsigned int uintx2;

#define S_LEN 2048
#define D_DIM 128
#define NBATCH 16
// (1/sqrt(128)) * log2(e): base-2 softmax, scale folded into Q conversion
#define QSC ((float)(0.08838834764831845 * 1.4426950408889634))
// fixed softmax shift: P = 2^(score - 8); exact by shift-invariance
#define MFIX 8.0f
#define E8 0.00390625f  // 2^-8, weight of a masked (score 0) position

#if __has_builtin(__builtin_amdgcn_exp2f)
#define EXP2(x) __builtin_amdgcn_exp2f(x)
#else
#define EXP2(x) exp2f(x)
#endif

DEVI unsigned short f2bf(float x) {
  union { float f; unsigned int u; } a; a.f = x;
  unsigned int u = a.u;
  unsigned int r = (u + 0x7fffu + ((u >> 16) & 1u)) >> 16;
  return (unsigned short)r;
}

DEVI unsigned int cvtpk(float lo, float hi) {
  unsigned int r;
  asm volatile("v_cvt_pk_bf16_f32 %0, %1, %2" : "=v"(r) : "v"(lo), "v"(hi));
  return r;
}

// v_permlane32_swap_b32: post: a = {a.lo | b.lo}, b = {a.hi | b.hi}  (R4-verified)
DEVI void plswap(unsigned int& a, unsigned int& b) {
  uintx2 r = __builtin_amdgcn_permlane32_swap(a, b, false, false);
  a = r[0];
  b = r[1];
}

DEVI float xhalf_sum(float x) {
  union { float f; unsigned int u; } a, b;
  a.f = x; b.f = x;
  plswap(a.u, b.u);
  return a.f + b.f;
}

// ---------------- prepass ----------------

// blocks [0,1024): V [b][s][d] fp32 -> Vt TILE-MAJOR [b][kt][d 0..127][64 keys] bf16
//                  + per-64-row tile sums
// blocks [1024,3072): K fp32 -> bf16 (row-major unchanged)
__global__ void prep(const float* __restrict__ K, const float* __restrict__ V,
                     unsigned short* __restrict__ Kb, unsigned short* __restrict__ Vt,
                     float* __restrict__ Tsum) {
  __shared__ unsigned short t[64][68];
  const int tt = threadIdx.x;
  if (blockIdx.x >= 1024) {
    const int M4 = (NBATCH * S_LEN * D_DIM) / 4;
    for (int i = (blockIdx.x - 1024) * 256 + tt; i < M4; i += 2048 * 256) {
      const size_t idx = (size_t)i * 4;
      const float4 v = *reinterpret_cast<const float4*>(K + idx);
      ushort4 o;
      o.x = f2bf(v.x); o.y = f2bf(v.y); o.z = f2bf(v.z); o.w = f2bf(v.w);
      *reinterpret_cast<ushort4*>(Kb + idx) = o;
    }
    return;
  }
  const int bid = blockIdx.x;
  const int b = bid >> 6, rem = bid & 63;
  const int st = rem & 31, s0 = st * 64, d0 = (rem >> 5) * 64;
  const int r = tt >> 2, c = (tt & 3) * 16;
  const float* src = V + ((size_t)(b * S_LEN + s0 + r)) * D_DIM + d0 + c;
#pragma unroll
  for (int i = 0; i < 4; i++) {
    float4 v = reinterpret_cast<const float4*>(src)[i];
    t[r][c + 4 * i + 0] = f2bf(v.x);
    t[r][c + 4 * i + 1] = f2bf(v.y);
    t[r][c + 4 * i + 2] = f2bf(v.z);
    t[r][c + 4 * i + 3] = f2bf(v.w);
  }
  __syncthreads();
  // tile-major: Vt[((b*32+st)*128 + d)*64 + key]
  unsigned short* dst = Vt + (((size_t)(b * 32 + st)) * 128 + d0 + r) * 64 + c;
#pragma unroll
  for (int i = 0; i < 4; i++) {
    ushort4 o;
    o.x = t[c + 4 * i + 0][r];
    o.y = t[c + 4 * i + 1][r];
    o.z = t[c + 4 * i + 2][r];
    o.w = t[c + 4 * i + 3][r];
    reinterpret_cast<ushort4*>(dst)[i] = o;
  }
  if (tt < 64) {
    float s = 0.0f;
#pragma unroll 8
    for (int rr = 0; rr < 64; rr++) {
      union { float f; unsigned int u; } cv;
      cv.u = ((unsigned int)t[rr][tt]) << 16;
      s += cv.f;
    }
    Tsum[((size_t)b * 32 + st) * 128 + d0 + tt] = s;
  }
}

// SufV[b][t][d] = sum_{t' >= t} Tsum[b][t'][d]; SufV[b][32][d] = 0
__global__ void sufB(const float* __restrict__ Tsum, float* __restrict__ SufV) {
  const int b = blockIdx.x;
  const int d = threadIdx.x;
  float v[32];
#pragma unroll
  for (int t = 0; t < 32; t++) v[t] = Tsum[((size_t)b * 32 + t) * 128 + d];
  float run = 0.0f;
  SufV[((size_t)b * 33 + 32) * 128 + d] = 0.0f;
#pragma unroll
  for (int t = 31; t >= 0; t--) {
    run += v[t];
    SufV[((size_t)b * 33 + t) * 128 + d] = run;
  }
}

// ---------------- attention kernel ----------------

#define AS1 __attribute__((address_space(1)))
#define AS3 __attribute__((address_space(3)))

DEVI short8 ldK(const char* ldsK, int row, int off) {
  int addr = row * 256 + (off ^ ((row & 15) << 4));
  return *reinterpret_cast<const short8*>(ldsK + addr);
}
DEVI short8 ldV(const char* ldsV, int row, int off) {
  int addr = row * 128 + (off ^ ((row & 7) << 4));
  return *reinterpret_cast<const short8*>(ldsV + addr);
}

// fixed-max tile body: P = 2^(s-8); no max tracking, no rescale
template <bool MASK>
DEVI void tile_body(const char* cb, const short8* qf, f32x16 (&acc)[4],
                    float& l_run, const int ln31, const int h, const int kh,
                    const int qrow, const int kvb) {
  f32x16 sT;
#pragma unroll
  for (int r = 0; r < 16; r++) sT[r] = 0.0f;
  __builtin_amdgcn_s_setprio(1);
#pragma unroll
  for (int kf = 0; kf < 8; kf++) {
    short8 af = ldK(cb, ln31 + 32 * kh, 32 * kf + 16 * h);
    sT = __builtin_amdgcn_mfma_f32_32x32x16_bf16(af, qf[kf], sT, 0, 0, 0);
  }
  __builtin_amdgcn_s_setprio(0);
  if (MASK) {
#pragma unroll
    for (int r = 0; r < 16; r++) {
      int kvg = kvb + (r & 3) + 8 * (r >> 2) + 4 * h;
      if (kvg > qrow) sT[r] = 0.0f;  // multiplicative mask; exp gives 2^-8
    }
  }
#pragma unroll
  for (int r = 0; r < 16; r++) sT[r] = EXP2(sT[r] - MFIX);
  float ts[8];
#pragma unroll
  for (int r = 0; r < 8; r++) ts[r] = sT[r] + sT[r + 8];
#pragma unroll
  for (int r = 0; r < 4; r++) ts[r] = ts[r] + ts[r + 4];
  float sum = (ts[0] + ts[1]) + (ts[2] + ts[3]);
  sum = xhalf_sum(sum);
  l_run += sum;
  // pack P -> bf16 A-fragments: u[0]={a.lo|b.lo}, u[2]={a.hi|b.hi} (R4-verified)
#pragma unroll
  for (int kl = 0; kl < 2; kl++) {
    const int ra = 8 * kl;
    const int rb = 8 * kl + 4;
    unsigned int a0 = cvtpk(sT[ra + 0], sT[ra + 1]);
    unsigned int a1 = cvtpk(sT[ra + 2], sT[ra + 3]);
    unsigned int b0 = cvtpk(sT[rb + 0], sT[rb + 1]);
    unsigned int b1 = cvtpk(sT[rb + 2], sT[rb + 3]);
    plswap(a0, b0);
    plswap(a1, b1);
    union { short8 v; unsigned int u[4]; } pa;
    pa.u[0] = a0; pa.u[1] = a1; pa.u[2] = b0; pa.u[3] = b1;
    const int vboff = 64 * kh + 32 * kl + 16 * h;
    __builtin_amdgcn_s_setprio(1);
#pragma unroll
    for (int nt = 0; nt < 4; nt++) {
      short8 vb = ldV(cb + 16384, ln31 + 32 * nt, vboff);
      acc[nt] = __builtin_amdgcn_mfma_f32_32x32x16_bf16(pa.v, vb, acc[nt], 0, 0, 0);
    }
    __builtin_amdgcn_s_setprio(0);
  }
}

// LDS: 4 tile buffers (2 dbuf x 2 grp) of 32KB (K 16K + V 16K) = 128KB,
// overlaid in epilogue by 8 partials (32x128 f32 = 16KB each) + l rows (1KB).
#define SMEM_BYTES 132096

struct WaveCtx {
  int w, lane, ln31, h, qs, grp, kh, tsel, dstpart;
  int off[8];
  const char* tbase;
};

DEVI void stage_tile(char* smem, const WaveCtx& c, int t, int j, int bi) {
  if (t <= j) {
    const char* src = c.tbase + (size_t)t * 16384;
    const int dbase = bi * 65536 + c.tsel * 32768 + c.dstpart;
#pragma unroll
    for (int i = 0; i < 8; i++) {
      __builtin_amdgcn_global_load_lds((const AS1 unsigned int*)(src + c.off[i]),
                                       (AS3 unsigned int*)(smem + dbase + i * 1024),
                                       16, 0, 0);
    }
  }
}

DEVI void run_strip(int j, int b, char* smem, const WaveCtx& c,
                    const float* __restrict__ Q, const float* __restrict__ SufV,
                    float* __restrict__ out) {
  const int q0 = j * 64;
  const int kv_end = q0 + 64;
  const int qrow = q0 + 32 * c.qs + c.ln31;

  // Q fragments (B-operand): frag kf element jj <-> d = 16*kf + 8*h + jj
  short8 qf[8];
  {
    const float* qsrc = Q + ((size_t)b * S_LEN + qrow) * D_DIM + 8 * c.h;
#pragma unroll
    for (int kf = 0; kf < 8; kf++) {
      float4 a = *reinterpret_cast<const float4*>(qsrc + 16 * kf);
      float4 d = *reinterpret_cast<const float4*>(qsrc + 16 * kf + 4);
      union { short8 v; unsigned int u[4]; } q8;
      q8.u[0] = cvtpk(a.x * QSC, a.y * QSC);
      q8.u[1] = cvtpk(a.z * QSC, a.w * QSC);
      q8.u[2] = cvtpk(d.x * QSC, d.y * QSC);
      q8.u[3] = cvtpk(d.z * QSC, d.w * QSC);
      qf[kf] = q8.v;
    }
  }

  f32x16 acc[4];
#pragma unroll
  for (int nt = 0; nt < 4; nt++)
#pragma unroll
    for (int rr = 0; rr < 16; rr++) acc[nt][rr] = 0.0f;
  float l_run = 0.0f;

  // phase loop: phase ph = tiles {2ph (grp0), 2ph+1 (grp1)}
  const int nph = (j >> 1) + 1;
  stage_tile(smem, c, c.tsel, j, 0);
  __syncthreads();
  int bi = 0;
  for (int ph = 0; ph < nph; ph++) {
    if (ph + 1 < nph) stage_tile(smem, c, 2 * (ph + 1) + c.tsel, j, bi ^ 1);
    const int t = 2 * ph + c.grp;
    if (t <= j) {
      const char* cb = smem + bi * 65536 + c.grp * 32768;
      if (t == j)
        tile_body<true>(cb, qf, acc, l_run, c.ln31, c.h, c.kh, qrow,
                        t * 64 + 32 * c.kh);
      else
        tile_body<false>(cb, qf, acc, l_run, c.ln31, c.h, c.kh, qrow,
                         t * 64 + 32 * c.kh);
    }
    __syncthreads();
    bi ^= 1;
  }

  // epilogue: all 8 waves write partial acc + l; then each wave reduces one
  // (qs, 32-col slice) of the 4 partials (fixed-max => plain sums)
  float* pbase = (float*)smem + c.w * 4096;
#pragma unroll
  for (int nt = 0; nt < 4; nt++)
#pragma unroll
    for (int rr = 0; rr < 16; rr++) {
      int cr = (rr & 3) + 8 * (rr >> 2) + 4 * c.h;
      pbase[cr * 128 + c.ln31 + 32 * nt] = acc[nt][rr];
    }
  float* lbase = (float*)(smem + 131072) + c.w * 32;
  if (c.h == 0) lbase[c.ln31] = l_run;
  __syncthreads();

  const int s = c.w & 3;
  const float* P0 = (float*)smem + (c.qs * 4) * 4096;
  const float* L0 = (float*)(smem + 131072) + (c.qs * 4) * 32;
  float l_tot = L0[c.ln31] + L0[32 + c.ln31] + L0[64 + c.ln31] + L0[96 + c.ln31];
  l_tot += (float)(S_LEN - kv_end) * E8;
  const float svv = SufV[((size_t)b * 33 + (kv_end >> 6)) * 128 + 32 * s + c.ln31];
  float* ob = out + ((size_t)b * S_LEN + q0 + 32 * c.qs) * D_DIM + 32 * s + c.ln31;
#pragma unroll
  for (int rr = 0; rr < 16; rr++) {
    int cr = (rr & 3) + 8 * (rr >> 2) + 4 * c.h;
    int cidx = cr * 128 + 32 * s + c.ln31;
    float v = P0[cidx] + P0[4096 + cidx] + P0[8192 + cidx] + P0[12288 + cidx];
    float lq = __shfl(l_tot, cr);
    ob[(size_t)cr * D_DIM] = (v + E8 * svv) / lq;
  }
  __syncthreads();  // protect overlay before next strip's staging
}

__global__ __launch_bounds__(512, 2) void attn_kernel(
    const float* __restrict__ Q, const unsigned short* __restrict__ Kb,
    const unsigned short* __restrict__ Vt, const float* __restrict__ SufV,
    float* __restrict__ out) {
  __shared__ __align__(16) char smem[SMEM_BYTES];

  WaveCtx c;
  const int tid = threadIdx.x;
  c.w = tid >> 6;
  c.lane = tid & 63;
  c.ln31 = c.lane & 31;
  c.h = c.lane >> 5;
  c.qs = c.w >> 2;
  c.grp = (c.w >> 1) & 1;
  c.kh = c.w & 1;
  c.tsel = c.w >> 2;  // staging: waves 0-3 -> even tile, 4-7 -> odd tile
  const int part = c.w & 3;

  // decode: XCD x owns batches {2x,2x+1}; block = (b, pair p): strips 31-p and p
  const int bid = blockIdx.x;
  const int x = bid & 7, idx = bid >> 3;
  const int b = 2 * x + (idx & 1);
  const int p = idx >> 1;

  // per-wave staging constants (R8-verified swizzle formulas, imm=0)
  if (part < 2) {
#pragma unroll
    for (int i = 0; i < 8; i++) {
      int L = (part * 8 + i) * 1024 + c.lane * 16;
      int row = L >> 8;
      c.off[i] = row * 256 + ((L & 255) ^ ((row & 15) << 4));
    }
    c.tbase = (const char*)(Kb + (size_t)b * S_LEN * D_DIM);
    c.dstpart = part * 8192;
  } else {
#pragma unroll
    for (int i = 0; i < 8; i++) {
      int L = ((part - 2) * 8 + i) * 1024 + c.lane * 16;
      int row = L >> 7;
      c.off[i] = (L & ~127) + ((L & 127) ^ ((row & 7) << 4));
    }
    c.tbase = (const char*)Vt + (size_t)b * (S_LEN * D_DIM * 2);
    c.dstpart = 16384 + (part - 2) * 8192;
  }

  run_strip(31 - p, b, smem, c, Q, SufV, out);
  run_strip(p, b, smem, c, Q, SufV, out);
}

// ---------------- launcher ----------------

extern "C" void kernel_launch(void* const* d_in, const int* in_sizes, int n_in,
                              void* d_out, int out_size, void* d_ws, size_t ws_size,
                              hipStream_t stream) {
  const float* Q = (const float*)d_in[0];
  const float* K = (const float*)d_in[1];
  const float* V = (const float*)d_in[2];
  float* out = (float*)d_out;

  char* ws = (char*)d_ws;
  unsigned short* Kb = (unsigned short*)ws;                 // 8 MiB
  unsigned short* Vt = Kb + 4194304;                        // 8 MiB (tile-major)
  float* Tsum = (float*)(ws + 16777216);                    // 256 KiB
  float* SufV = Tsum + 65536;                               // 264 KiB

  prep<<<3072, 256, 0, stream>>>(K, V, Kb, Vt, Tsum);
  sufB<<<16, 128, 0, stream>>>(Tsum, SufV);
  attn_kernel<<<256, 512, 0, stream>>>(Q, Kb, Vt, SufV, out);
}